// Round 9
// baseline (93.307 us; speedup 1.0000x reference)
//
#include <hip/hip_runtime.h>
#include <hip/hip_bf16.h>
#include <math.h>

#define NS 480   // n*s
#define NN 16
#define SS 30
#define CC 64
#define HHH 64
#define WW 22
#define PP 7
#define MAXH 22
#define CP 64
#define VV 17
#define DD 1536
#define OC 256
#define SILD 1408   // c*MAXH
#define NTOK 3360   // NS*PP

typedef __bf16 bf16x8 __attribute__((ext_vector_type(8)));
typedef float f32x4 __attribute__((ext_vector_type(4)));
typedef short short8 __attribute__((ext_vector_type(8)));

__device__ __forceinline__ void gl_lds16(const void* g, void* l) {
    __builtin_amdgcn_global_load_lds(
        (const __attribute__((address_space(1))) void*)g,
        (__attribute__((address_space(3))) void*)l, 16, 0, 0);
}

__device__ __forceinline__ float bf2f(short s) {
    union { float f; unsigned u; } uu; uu.u = ((unsigned)(unsigned short)s) << 16; return uu.f;
}

// ============ K1: pool+gather (8 triples/block, gl_lds streaming) + weight/pose prep ============
__global__ __launch_bounds__(256) void prep(const float* __restrict__ sil,
                                            const int* __restrict__ min_idx,
                                            const float* __restrict__ wqkv,
                                            const float* __restrict__ wproj,
                                            const float* __restrict__ fcbin,
                                            const float* __restrict__ pose,
                                            __hip_bfloat16* __restrict__ fuse,
                                            __hip_bfloat16* __restrict__ wqkv16,
                                            __hip_bfloat16* __restrict__ wproj16,
                                            __hip_bfloat16* __restrict__ fcbinT16) {
    __shared__ __align__(16) char smem[47552];
    int b = blockIdx.x, tid = threadIdx.x;
    if (b < 3840) {
        // 8 (n,c,s) triples x 64 h x 22 w = 45056 B streamed via global_load_lds
        float* lds  = (float*)smem;             // 11264 floats
        float* hbuf = (float*)(smem + 45056);   // 512 floats [qi*64+h]
        int*   mi_s = (int*)(smem + 47104);     // 112 ints
        if (tid < 112) mi_s[tid] = min_idx[tid];
        long long base = (long long)b * 11264;
        int w = tid >> 6, lane = tid & 63;
        const char* gsrc = (const char*)(sil + base) + lane * 16;
        #pragma unroll
        for (int i = 0; i < 11; i++) {
            int ci = w * 11 + i;
            gl_lds16(gsrc + ci * 1024, (char*)smem + ci * 1024);
        }
        __syncthreads();   // drains vmcnt + lgkm
        #pragma unroll
        for (int rr = 0; rr < 2; rr++) {
            int r = tid + rr * 256;          // 0..511 = qi*64 + h
            const float* row = lds + r * 22;
            float s = 0.f, m = -INFINITY;
            #pragma unroll
            for (int k = 0; k < WW; k++) { float v = row[k]; s += v; m = fmaxf(m, v); }
            hbuf[r] = s * (1.0f / WW) + m;
        }
        __syncthreads();
        int q0 = b * 8;       // q = (n*64 + c)*30 + s
        for (int idx = tid; idx < 8 * PP * MAXH; idx += 256) {
            int hh = idx % MAXH;
            int t2 = idx / MAXH;
            int j = t2 % PP, qi = t2 / PP;
            int q = q0 + qi;
            int s_i = q % SS, t3 = q / SS;
            int c = t3 & 63, n = t3 >> 6;
            int mi = mi_s[j * NN + n];
            fuse[((long long)(j * NS + n * SS + s_i)) * DD + c * MAXH + hh] =
                __float2bfloat16(hbuf[qi * 64 + mi + hh]);
        }
        return;
    }
    b -= 3840;
    if (b < 768)  { int g = b * 256 + tid; wqkv16[g] = __float2bfloat16(wqkv[g]); return; }
    if (b < 1024) { int g = (b - 768) * 256 + tid; wproj16[g] = __float2bfloat16(wproj[g]); return; }
    if (b < 1696) {
        float (*t)[65] = (float(*)[65])smem;   // 16640 B
        int bb = b - 1024;                     // 0..671
        int p = bb / 96, r2 = bb % 96, dt = r2 / 4, ot = r2 % 4;
        const float* s = fcbin + ((long long)p * DD + dt * 64) * OC + ot * 64;
        for (int i = tid; i < 64 * 64; i += 256) {
            int r = i >> 6, c = i & 63;
            t[r][c] = s[(long long)r * OC + c];
        }
        __syncthreads();
        __hip_bfloat16* d = fcbinT16 + ((long long)p * OC + ot * 64) * DD + dt * 64;
        for (int i = tid; i < 64 * 64; i += 256) {
            int r = i >> 6, c = i & 63;
            d[(long long)r * DD + c] = __float2bfloat16(t[c][r]);
        }
        return;
    }
    // pose columns of fuse: 7*480*128 elements
    int g = (b - 1696) * 256 + tid;
    int dd = g & 127;
    int t2 = g >> 7;
    int nsi = t2 % NS;
    int j = t2 / NS;
    int n = nsi / SS, s_i = nsi % SS;
    int cpi = dd >> 1, par = dd & 1;
    const float* pr = pose + (((long long)n * CP + cpi) * SS + s_i) * VV;
    float v;
    if (j == 0) {
        v = (par == 0) ? (pr[0] + pr[1] + pr[2]) * (1.f / 3.f)
                       : (pr[2] + pr[3] + pr[4]) * (1.f / 3.f);
    } else {
        v = pr[5 + (j - 1) * 2 + par];
    }
    v = (v > 0.f) ? v : 0.01f * v;
    fuse[(long long)(j * NS + nsi) * DD + SILD + dd] = __float2bfloat16(v);
}

// ============ K2: fc MFMA GEMM, 8 waves via K-split (2 groups x 768), 2-phase dbuf, + BN partials ============
__global__ __launch_bounds__(512) void gemm_fc(
    const __hip_bfloat16* __restrict__ Ain, const __hip_bfloat16* __restrict__ Bt,
    float* __restrict__ Cf, float* __restrict__ partial)
{
    const int M = 480, K = 1536, lda = 1536, ldc = 1792;
    const __hip_bfloat16* Ab = Ain + (long long)blockIdx.z * 480 * 1536;
    const __hip_bfloat16* Bq = Bt + (long long)blockIdx.z * 256 * 1536;
    float* C = Cf + (long long)blockIdx.z * 256;

    __shared__ short As[2][2][4096];      // [kgroup][buf]
    __shared__ short Bs[2][2][4096];
    __shared__ float red[4][2][16][2];

    int tid = threadIdx.x, lane = tid & 63, w = tid >> 6;   // w: 0..7
    int kg = w >> 2, wq = w & 3;
    int wm = wq >> 1, wn = wq & 1;
    int row0 = blockIdx.x * 64, col0 = blockIdx.y * 64;
    int kbase = kg * 768;                 // each group: 12 K-steps of 64

    f32x4 acc[2][2] = {};

    auto stage = [&](int buf, int k0) {   // k0 relative to kbase
        int cc = lane & 7;
        #pragma unroll
        for (int i = 0; i < 2; i++) {
            int r = wq * 16 + i * 8 + (lane >> 3);
            int grow = row0 + r; if (grow >= M) grow = M - 1;
            long long kk = kbase + k0;
            const char* ga = (const char*)Ab + (((long long)grow * lda + kk) << 1) + ((cc ^ (r & 7)) << 4);
            gl_lds16(ga, (char*)&As[kg][buf][0] + (wq * 16 + i * 8) * 128);
            const char* gb = (const char*)Bq + (((long long)(col0 + r) * K + kk) << 1) + ((cc ^ (r & 7)) << 4);
            gl_lds16(gb, (char*)&Bs[kg][buf][0] + (wq * 16 + i * 8) * 128);
        }
    };

    stage(0, 0);
    __syncthreads();
    for (int t = 0; t < 12; t++) {
        int cur = t & 1;
        if (t + 1 < 12) stage(cur ^ 1, (t + 1) << 6);
        #pragma unroll
        for (int ks = 0; ks < 2; ks++) {
            bf16x8 af[2], bfv[2];
            #pragma unroll
            for (int f = 0; f < 2; f++) {
                int r = wm * 32 + f * 16 + (lane & 15);
                int ca = (ks * 4 + (lane >> 4)) ^ (r & 7);
                af[f] = *(const bf16x8*)((const char*)&As[kg][cur][0] + r * 128 + (ca << 4));
                int rb = wn * 32 + f * 16 + (lane & 15);
                int cb = (ks * 4 + (lane >> 4)) ^ (rb & 7);
                bfv[f] = *(const bf16x8*)((const char*)&Bs[kg][cur][0] + rb * 128 + (cb << 4));
            }
            #pragma unroll
            for (int fm = 0; fm < 2; fm++)
                #pragma unroll
                for (int fn = 0; fn < 2; fn++)
                    acc[fm][fn] = __builtin_amdgcn_mfma_f32_16x16x32_bf16(
                        af[fm], bfv[fn], acc[fm][fn], 0, 0, 0);
        }
        __syncthreads();
    }

    // cross-group reduce: group 1 -> LDS, group 0 adds
    float* redC = (float*)&As[0][0][0];   // 16 KB, safe after final sync
    if (kg == 1) {
        #pragma unroll
        for (int fm = 0; fm < 2; fm++)
            #pragma unroll
            for (int fn = 0; fn < 2; fn++)
                #pragma unroll
                for (int r4 = 0; r4 < 4; r4++) {
                    int rl = wm * 32 + fm * 16 + (lane >> 4) * 4 + r4;
                    int cl = wn * 32 + fn * 16 + (lane & 15);
                    redC[rl * 64 + cl] = acc[fm][fn][r4];
                }
    }
    __syncthreads();

    if (kg == 0) {
        float s[2] = {0.f, 0.f}, s2[2] = {0.f, 0.f};
        #pragma unroll
        for (int fm = 0; fm < 2; fm++) {
            #pragma unroll
            for (int fn = 0; fn < 2; fn++) {
                #pragma unroll
                for (int r4 = 0; r4 < 4; r4++) {
                    int rl = wm * 32 + fm * 16 + (lane >> 4) * 4 + r4;
                    int cl = wn * 32 + fn * 16 + (lane & 15);
                    int grow = row0 + rl;
                    if (grow < M) {
                        float v = acc[fm][fn][r4] + redC[rl * 64 + cl];
                        C[(long long)grow * ldc + col0 + cl] = v;
                        s[fn] += v; s2[fn] += v * v;
                    }
                }
            }
        }
        #pragma unroll
        for (int off = 16; off < 64; off <<= 1) {
            s[0] += __shfl_xor(s[0], off);  s2[0] += __shfl_xor(s2[0], off);
            s[1] += __shfl_xor(s[1], off);  s2[1] += __shfl_xor(s2[1], off);
        }
        if (lane < 16) {
            red[wq][0][lane][0] = s[0]; red[wq][0][lane][1] = s2[0];
            red[wq][1][lane][0] = s[1]; red[wq][1][lane][1] = s2[1];
        }
    }
    __syncthreads();
    if (tid < 128) {
        int col = tid >> 1, which = tid & 1;
        int wn2 = (col >> 5) & 1, fn2 = (col >> 4) & 1, c16 = col & 15;
        float v = red[wn2][fn2][c16][which] + red[2 + wn2][fn2][c16][which];
        partial[((long long)(blockIdx.z * 8 + blockIdx.x) * 2 + which) * 256 + blockIdx.y * 64 + col] = v;
    }
}

// ============ K3: BN-final + qkv GEMM + attention + proj + residual + transposed out ============
// block = 7 tokens (1 attn batch); 480 blocks; ~50KB LDS -> 3 blocks/CU.
__global__ __launch_bounds__(256) void qkvattn(const float* __restrict__ xraw,
                                               const __hip_bfloat16* __restrict__ wqkv16,
                                               const __hip_bfloat16* __restrict__ wproj16,
                                               const float* __restrict__ partial,
                                               const float* __restrict__ gamma,
                                               const float* __restrict__ beta,
                                               float* __restrict__ outp) {
    __shared__ short As[16 * 256];        // swizzled BN(x) bf16 tile (rows 7..15 zero)
    __shared__ float qkvs[7 * 768];
    __shared__ float as_[8][49];
    __shared__ short ao_s[16 * 256];
    __shared__ float Ct[256 * 9];
    __shared__ float ssl[512];

    int tid = threadIdx.x, lane = tid & 63, w = tid >> 6;
    int token0 = blockIdx.x * 7;

    // BN final (redundant per block, deterministic): thread = channel
    {
        float s = 0.f, s2 = 0.f;
        #pragma unroll 8
        for (int bb = 0; bb < 56; bb++) {
            s  += partial[bb * 512 + tid];
            s2 += partial[bb * 512 + 256 + tid];
        }
        float mu = s * (1.f / NTOK);
        float var = s2 * (1.f / NTOK) - mu * mu;
        float rsig = rsqrtf(var + 1e-5f);
        float sc = gamma[tid] * rsig;
        ssl[tid] = sc;
        ssl[256 + tid] = beta[tid] - mu * sc;
    }
    __syncthreads();

    // stage BN(x) -> As (16 rows x 256 k, rows 7..15 zero), XOR-swizzled 16B chunks
    for (int i = tid; i < 512; i += 256) {
        int r = i >> 5, c8 = i & 31;
        short8 o = {};
        if (r < 7) {
            const float* src = xraw + (long long)(token0 + r) * 256 + c8 * 8;
            float4 v0 = *(const float4*)src;
            float4 v1 = *(const float4*)(src + 4);
            float vv[8] = {v0.x, v0.y, v0.z, v0.w, v1.x, v1.y, v1.z, v1.w};
            #pragma unroll
            for (int j2 = 0; j2 < 8; j2++) {
                float tv = vv[j2] * ssl[c8 * 8 + j2] + ssl[256 + c8 * 8 + j2];
                union { __hip_bfloat16 h; short s; } u; u.h = __float2bfloat16(tv);
                o[j2] = u.s;
            }
        }
        *(short8*)&As[r * 256 + ((c8 ^ (r & 7)) << 3)] = o;
    }
    __syncthreads();

    // qkv GEMM: wave w covers output cols [w*192, (w+1)*192); B-frags from L2
    {
        f32x4 qacc[12] = {};
        int n0w = w * 192;
        #pragma unroll
        for (int k0 = 0; k0 < 256; k0 += 32) {
            int r = lane & 15;
            int kk = k0 + (lane >> 4) * 8;
            int ck = kk >> 3;
            bf16x8 af = *(const bf16x8*)(const void*)&As[r * 256 + ((ck ^ (r & 7)) << 3)];
            #pragma unroll
            for (int fn = 0; fn < 12; fn++) {
                int nn2 = n0w + fn * 16 + (lane & 15);
                bf16x8 bv = *(const bf16x8*)(const void*)((const short*)wqkv16 + nn2 * 256 + kk);
                qacc[fn] = __builtin_amdgcn_mfma_f32_16x16x32_bf16(af, bv, qacc[fn], 0, 0, 0);
            }
        }
        #pragma unroll
        for (int fn = 0; fn < 12; fn++)
            #pragma unroll
            for (int r4 = 0; r4 < 4; r4++) {
                int row = (lane >> 4) * 4 + r4;
                if (row < 7) qkvs[row * 768 + n0w + fn * 16 + (lane & 15)] = qacc[fn][r4];
            }
    }
    __syncthreads();

    // attention scores (softmax over HEADS)
    for (int t = tid; t < 392; t += 256) {
        int h = t / 49, ij = t % 49, i = ij / 7, j = ij % 7;
        const float* qp = qkvs + i * 768 + h * 32;
        const float* kp = qkvs + j * 768 + 256 + h * 32;
        float acc = 0.f;
        #pragma unroll
        for (int d = 0; d < 32; d++) acc += qp[d] * kp[d];
        as_[h][ij] = acc * 0.17677669529663689f;
    }
    __syncthreads();
    if (tid < 49) {
        float m = -INFINITY;
        #pragma unroll
        for (int h = 0; h < 8; h++) m = fmaxf(m, as_[h][tid]);
        float e[8], sum = 0.f;
        #pragma unroll
        for (int h = 0; h < 8; h++) { e[h] = __expf(as_[h][tid] - m); sum += e[h]; }
        float inv = 1.f / sum;
        #pragma unroll
        for (int h = 0; h < 8; h++) as_[h][tid] = e[h] * inv;
    }
    __syncthreads();
    // ao rows (pads zero), XOR-swizzled bf16 store for proj A-frags
    #pragma unroll
    for (int it = 0; it < 16; it++) {
        int tl = it, col = tid;
        float acc = 0.f;
        if (tl < 7) {
            int h = col >> 5;
            const float* ap = &as_[h][tl * 7];
            const float* vp = qkvs + 512 + col;
            #pragma unroll
            for (int j = 0; j < 7; j++) acc += ap[j] * vp[j * 768];
        }
        int c16 = col >> 3;
        union { __hip_bfloat16 h2; short s2; } u; u.h2 = __float2bfloat16(acc);
        ao_s[tl * 256 + ((c16 ^ (tl & 7)) << 3) + (col & 7)] = u.s2;
    }
    __syncthreads();
    // proj MFMA: wave w -> output cols n0 = w*64; B direct from L2 (wproj16 [N][K])
    f32x4 pacc[4] = {};
    int n0 = w * 64;
    #pragma unroll
    for (int k0 = 0; k0 < 256; k0 += 32) {
        int rowa = lane & 15;
        int kk = k0 + (lane >> 4) * 8;
        int c16a = kk >> 3;
        bf16x8 af = *(const bf16x8*)(const void*)&ao_s[rowa * 256 + ((c16a ^ (rowa & 7)) << 3)];
        #pragma unroll
        for (int fn = 0; fn < 4; fn++) {
            int n = n0 + fn * 16 + (lane & 15);
            bf16x8 bfv = *(const bf16x8*)(const void*)((const short*)wproj16 + n * 256 + kk);
            pacc[fn] = __builtin_amdgcn_mfma_f32_16x16x32_bf16(af, bfv, pacc[fn], 0, 0, 0);
        }
    }
    #pragma unroll
    for (int fn = 0; fn < 4; fn++)
        #pragma unroll
        for (int r4 = 0; r4 < 4; r4++) {
            int tk = (lane >> 4) * 4 + r4;
            if (tk < 7) {
                int o = n0 + fn * 16 + (lane & 15);
                Ct[o * 9 + tk] = pacc[fn][r4];
            }
        }
    __syncthreads();
    // residual(BN(xraw)) + transposed write: thread = output channel o
    int o = tid;
    int n = token0 / 210, rem0 = token0 % 210;   // 210 = 30*7: never straddles n
    float* op = outp + ((long long)(n * 256 + o)) * 210 + rem0;
    float sc = ssl[o], sh = ssl[256 + o];
    #pragma unroll
    for (int tk = 0; tk < 7; tk++) {
        op[tk] = Ct[o * 9 + tk] + xraw[(long long)(token0 + tk) * 256 + o] * sc + sh;
    }
}

extern "C" void kernel_launch(void* const* d_in, const int* in_sizes, int n_in,
                              void* d_out, int out_size, void* d_ws, size_t ws_size,
                              hipStream_t stream) {
    const float* sil   = (const float*)d_in[0];
    const float* pose  = (const float*)d_in[1];
    const float* fcbin = (const float*)d_in[2];
    const float* gamma = (const float*)d_in[3];
    const float* beta  = (const float*)d_in[4];
    const float* wqkv  = (const float*)d_in[5];
    const float* wproj = (const float*)d_in[6];
    const int*   minidx= (const int*)d_in[7];
    float* out = (float*)d_out;

    float* ws = (float*)d_ws;
    __hip_bfloat16* fuse16   = (__hip_bfloat16*)ws;             // 5,160,960 bf16
    float* xraw    = ws + 2580480;                              // 860,160 f32 (ldc=1792 view)
    float* partial = ws + 3440640;                              // 28,672
    __hip_bfloat16* wqkv16   = (__hip_bfloat16*)(ws + 3469312); // 196,608 bf16
    __hip_bfloat16* wproj16  = (__hip_bfloat16*)(ws + 3567616); // 65,536 bf16
    __hip_bfloat16* fcbinT16 = (__hip_bfloat16*)(ws + 3600384); // 2,752,512 bf16

    prep<<<7216, 256, 0, stream>>>(sil, minidx, wqkv, wproj, fcbin, pose,
                                   fuse16, wqkv16, wproj16, fcbinT16);
    gemm_fc<<<dim3(8, 4, 7), 512, 0, stream>>>(fuse16, fcbinT16, xraw, partial);
    qkvattn<<<480, 256, 0, stream>>>(xraw, wqkv16, wproj16, partial, gamma, beta, out);
}

// Round 10
// 81.192 us; speedup vs baseline: 1.1492x; 1.1492x over previous
//
#include <hip/hip_runtime.h>
#include <hip/hip_bf16.h>
#include <math.h>

#define NS 480   // n*s
#define NN 16
#define SS 30
#define CC 64
#define HHH 64
#define WW 22
#define PP 7
#define MAXH 22
#define CP 64
#define VV 17
#define DD 1536
#define OC 256
#define SILD 1408   // c*MAXH
#define NTOK 3360   // NS*PP

typedef __bf16 bf16x8 __attribute__((ext_vector_type(8)));
typedef float f32x4 __attribute__((ext_vector_type(4)));
typedef short short8 __attribute__((ext_vector_type(8)));

__device__ __forceinline__ void gl_lds16(const void* g, void* l) {
    __builtin_amdgcn_global_load_lds(
        (const __attribute__((address_space(1))) void*)g,
        (__attribute__((address_space(3))) void*)l, 16, 0, 0);
}

__device__ __forceinline__ float bf2f(short s) {
    union { float f; unsigned u; } uu; uu.u = ((unsigned)(unsigned short)s) << 16; return uu.f;
}

// ============ K1: pool+gather (8 triples/block, gl_lds streaming) + weight/pose prep ============
__global__ __launch_bounds__(256) void prep(const float* __restrict__ sil,
                                            const int* __restrict__ min_idx,
                                            const float* __restrict__ wqkv,
                                            const float* __restrict__ wproj,
                                            const float* __restrict__ fcbin,
                                            const float* __restrict__ pose,
                                            __hip_bfloat16* __restrict__ fuse,
                                            __hip_bfloat16* __restrict__ wqkv16,
                                            __hip_bfloat16* __restrict__ wproj16,
                                            __hip_bfloat16* __restrict__ fcbinT16) {
    __shared__ __align__(16) char smem[47552];
    int b = blockIdx.x, tid = threadIdx.x;
    if (b < 3840) {
        // 8 (n,c,s) triples x 64 h x 22 w = 45056 B streamed via global_load_lds
        float* lds  = (float*)smem;             // 11264 floats
        float* hbuf = (float*)(smem + 45056);   // 512 floats [qi*64+h]
        int*   mi_s = (int*)(smem + 47104);     // 112 ints
        if (tid < 112) mi_s[tid] = min_idx[tid];
        long long base = (long long)b * 11264;
        int w = tid >> 6, lane = tid & 63;
        const char* gsrc = (const char*)(sil + base) + lane * 16;
        #pragma unroll
        for (int i = 0; i < 11; i++) {
            int ci = w * 11 + i;
            gl_lds16(gsrc + ci * 1024, (char*)smem + ci * 1024);
        }
        __syncthreads();   // drains vmcnt + lgkm
        #pragma unroll
        for (int rr = 0; rr < 2; rr++) {
            int r = tid + rr * 256;          // 0..511 = qi*64 + h
            const float* row = lds + r * 22;
            float s = 0.f, m = -INFINITY;
            #pragma unroll
            for (int k = 0; k < WW; k++) { float v = row[k]; s += v; m = fmaxf(m, v); }
            hbuf[r] = s * (1.0f / WW) + m;
        }
        __syncthreads();
        int q0 = b * 8;       // q = (n*64 + c)*30 + s
        for (int idx = tid; idx < 8 * PP * MAXH; idx += 256) {
            int hh = idx % MAXH;
            int t2 = idx / MAXH;
            int j = t2 % PP, qi = t2 / PP;
            int q = q0 + qi;
            int s_i = q % SS, t3 = q / SS;
            int c = t3 & 63, n = t3 >> 6;
            int mi = mi_s[j * NN + n];
            fuse[((long long)(j * NS + n * SS + s_i)) * DD + c * MAXH + hh] =
                __float2bfloat16(hbuf[qi * 64 + mi + hh]);
        }
        return;
    }
    b -= 3840;
    if (b < 768)  { int g = b * 256 + tid; wqkv16[g] = __float2bfloat16(wqkv[g]); return; }
    if (b < 1024) { int g = (b - 768) * 256 + tid; wproj16[g] = __float2bfloat16(wproj[g]); return; }
    if (b < 1696) {
        float (*t)[65] = (float(*)[65])smem;   // 16640 B
        int bb = b - 1024;                     // 0..671
        int p = bb / 96, r2 = bb % 96, dt = r2 / 4, ot = r2 % 4;
        const float* s = fcbin + ((long long)p * DD + dt * 64) * OC + ot * 64;
        for (int i = tid; i < 64 * 64; i += 256) {
            int r = i >> 6, c = i & 63;
            t[r][c] = s[(long long)r * OC + c];
        }
        __syncthreads();
        __hip_bfloat16* d = fcbinT16 + ((long long)p * OC + ot * 64) * DD + dt * 64;
        for (int i = tid; i < 64 * 64; i += 256) {
            int r = i >> 6, c = i & 63;
            d[(long long)r * DD + c] = __float2bfloat16(t[c][r]);
        }
        return;
    }
    // pose columns of fuse: 7*480*128 elements
    int g = (b - 1696) * 256 + tid;
    int dd = g & 127;
    int t2 = g >> 7;
    int nsi = t2 % NS;
    int j = t2 / NS;
    int n = nsi / SS, s_i = nsi % SS;
    int cpi = dd >> 1, par = dd & 1;
    const float* pr = pose + (((long long)n * CP + cpi) * SS + s_i) * VV;
    float v;
    if (j == 0) {
        v = (par == 0) ? (pr[0] + pr[1] + pr[2]) * (1.f / 3.f)
                       : (pr[2] + pr[3] + pr[4]) * (1.f / 3.f);
    } else {
        v = pr[5 + (j - 1) * 2 + par];
    }
    v = (v > 0.f) ? v : 0.01f * v;
    fuse[(long long)(j * NS + nsi) * DD + SILD + dd] = __float2bfloat16(v);
}

// ============ K2: fc MFMA GEMM, 8 waves via K-split (2 groups x 768), 2-phase dbuf, + BN partials ============
__global__ __launch_bounds__(512) void gemm_fc(
    const __hip_bfloat16* __restrict__ Ain, const __hip_bfloat16* __restrict__ Bt,
    float* __restrict__ Cf, float* __restrict__ partial)
{
    const int M = 480, K = 1536, lda = 1536, ldc = 1792;
    const __hip_bfloat16* Ab = Ain + (long long)blockIdx.z * 480 * 1536;
    const __hip_bfloat16* Bq = Bt + (long long)blockIdx.z * 256 * 1536;
    float* C = Cf + (long long)blockIdx.z * 256;

    __shared__ short As[2][2][4096];      // [kgroup][buf]
    __shared__ short Bs[2][2][4096];
    __shared__ float red[4][2][16][2];

    int tid = threadIdx.x, lane = tid & 63, w = tid >> 6;   // w: 0..7
    int kg = w >> 2, wq = w & 3;
    int wm = wq >> 1, wn = wq & 1;
    int row0 = blockIdx.x * 64, col0 = blockIdx.y * 64;
    int kbase = kg * 768;                 // each group: 12 K-steps of 64

    f32x4 acc[2][2] = {};

    auto stage = [&](int buf, int k0) {   // k0 relative to kbase
        int cc = lane & 7;
        #pragma unroll
        for (int i = 0; i < 2; i++) {
            int r = wq * 16 + i * 8 + (lane >> 3);
            int grow = row0 + r; if (grow >= M) grow = M - 1;
            long long kk = kbase + k0;
            const char* ga = (const char*)Ab + (((long long)grow * lda + kk) << 1) + ((cc ^ (r & 7)) << 4);
            gl_lds16(ga, (char*)&As[kg][buf][0] + (wq * 16 + i * 8) * 128);
            const char* gb = (const char*)Bq + (((long long)(col0 + r) * K + kk) << 1) + ((cc ^ (r & 7)) << 4);
            gl_lds16(gb, (char*)&Bs[kg][buf][0] + (wq * 16 + i * 8) * 128);
        }
    };

    stage(0, 0);
    __syncthreads();
    for (int t = 0; t < 12; t++) {
        int cur = t & 1;
        if (t + 1 < 12) stage(cur ^ 1, (t + 1) << 6);
        #pragma unroll
        for (int ks = 0; ks < 2; ks++) {
            bf16x8 af[2], bfv[2];
            #pragma unroll
            for (int f = 0; f < 2; f++) {
                int r = wm * 32 + f * 16 + (lane & 15);
                int ca = (ks * 4 + (lane >> 4)) ^ (r & 7);
                af[f] = *(const bf16x8*)((const char*)&As[kg][cur][0] + r * 128 + (ca << 4));
                int rb = wn * 32 + f * 16 + (lane & 15);
                int cb = (ks * 4 + (lane >> 4)) ^ (rb & 7);
                bfv[f] = *(const bf16x8*)((const char*)&Bs[kg][cur][0] + rb * 128 + (cb << 4));
            }
            #pragma unroll
            for (int fm = 0; fm < 2; fm++)
                #pragma unroll
                for (int fn = 0; fn < 2; fn++)
                    acc[fm][fn] = __builtin_amdgcn_mfma_f32_16x16x32_bf16(
                        af[fm], bfv[fn], acc[fm][fn], 0, 0, 0);
        }
        __syncthreads();
    }

    // cross-group reduce: group 1 -> LDS, group 0 adds
    float* redC = (float*)&As[0][0][0];   // 16 KB, safe after final sync
    if (kg == 1) {
        #pragma unroll
        for (int fm = 0; fm < 2; fm++)
            #pragma unroll
            for (int fn = 0; fn < 2; fn++)
                #pragma unroll
                for (int r4 = 0; r4 < 4; r4++) {
                    int rl = wm * 32 + fm * 16 + (lane >> 4) * 4 + r4;
                    int cl = wn * 32 + fn * 16 + (lane & 15);
                    redC[rl * 64 + cl] = acc[fm][fn][r4];
                }
    }
    __syncthreads();

    if (kg == 0) {
        float s[2] = {0.f, 0.f}, s2[2] = {0.f, 0.f};
        #pragma unroll
        for (int fm = 0; fm < 2; fm++) {
            #pragma unroll
            for (int fn = 0; fn < 2; fn++) {
                #pragma unroll
                for (int r4 = 0; r4 < 4; r4++) {
                    int rl = wm * 32 + fm * 16 + (lane >> 4) * 4 + r4;
                    int cl = wn * 32 + fn * 16 + (lane & 15);
                    int grow = row0 + rl;
                    if (grow < M) {
                        float v = acc[fm][fn][r4] + redC[rl * 64 + cl];
                        C[(long long)grow * ldc + col0 + cl] = v;
                        s[fn] += v; s2[fn] += v * v;
                    }
                }
            }
        }
        #pragma unroll
        for (int off = 16; off < 64; off <<= 1) {
            s[0] += __shfl_xor(s[0], off);  s2[0] += __shfl_xor(s2[0], off);
            s[1] += __shfl_xor(s[1], off);  s2[1] += __shfl_xor(s2[1], off);
        }
        if (lane < 16) {
            red[wq][0][lane][0] = s[0]; red[wq][0][lane][1] = s2[0];
            red[wq][1][lane][0] = s[1]; red[wq][1][lane][1] = s2[1];
        }
    }
    __syncthreads();
    if (tid < 128) {
        int col = tid >> 1, which = tid & 1;
        int wn2 = (col >> 5) & 1, fn2 = (col >> 4) & 1, c16 = col & 15;
        float v = red[wn2][fn2][c16][which] + red[2 + wn2][fn2][c16][which];
        partial[((long long)(blockIdx.z * 8 + blockIdx.x) * 2 + which) * 256 + blockIdx.y * 64 + col] = v;
    }
}

// ============ K3: BN-final + qkv GEMM + attention + proj + residual + transposed out ============
// block = 14 tokens (2 attn batches); 240 blocks. LDS aliased: 56.4KB -> 2 blocks/CU.
__global__ __launch_bounds__(256) void qkvattn(const float* __restrict__ xraw,
                                               const __hip_bfloat16* __restrict__ wqkv16,
                                               const __hip_bfloat16* __restrict__ wproj16,
                                               const float* __restrict__ partial,
                                               const float* __restrict__ gamma,
                                               const float* __restrict__ beta,
                                               float* __restrict__ outp) {
    __shared__ __align__(16) char sm[56384];
    float* qkvs = (float*)sm;                         // [14*768] f32 (dead after ao phase)
    float* Ct   = (float*)sm;                         // [256*17] f32 — aliases qkvs
    short* As   = (short*)(sm + 43008);               // [16*256] swizzled bf16 (dead after qkv GEMM)
    short* ao_s = (short*)(sm + 43008);               // aliases As
    float (*as_)[8][49] = (float(*)[8][49])(sm + 51200);  // 3136 B
    float* ssl  = (float*)(sm + 54336);               // 2048 B

    int tid = threadIdx.x, lane = tid & 63, w = tid >> 6;
    int token0 = blockIdx.x * 14;

    // BN final (redundant per block, deterministic): thread = channel
    {
        float s = 0.f, s2 = 0.f;
        #pragma unroll 8
        for (int bb = 0; bb < 56; bb++) {
            s  += partial[bb * 512 + tid];
            s2 += partial[bb * 512 + 256 + tid];
        }
        float mu = s * (1.f / NTOK);
        float var = s2 * (1.f / NTOK) - mu * mu;
        float rsig = rsqrtf(var + 1e-5f);
        float sc = gamma[tid] * rsig;
        ssl[tid] = sc;
        ssl[256 + tid] = beta[tid] - mu * sc;
    }
    __syncthreads();

    // stage BN(x) -> As (16 rows x 256 k, rows 14/15 zero), XOR-swizzled 16B chunks
    for (int i = tid; i < 512; i += 256) {
        int r = i >> 5, c8 = i & 31;
        short8 o = {};
        if (r < 14) {
            const float* src = xraw + (long long)(token0 + r) * 256 + c8 * 8;
            float4 v0 = *(const float4*)src;
            float4 v1 = *(const float4*)(src + 4);
            float vv[8] = {v0.x, v0.y, v0.z, v0.w, v1.x, v1.y, v1.z, v1.w};
            #pragma unroll
            for (int j2 = 0; j2 < 8; j2++) {
                float tv = vv[j2] * ssl[c8 * 8 + j2] + ssl[256 + c8 * 8 + j2];
                union { __hip_bfloat16 h; short s; } u; u.h = __float2bfloat16(tv);
                o[j2] = u.s;
            }
        }
        *(short8*)&As[r * 256 + ((c8 ^ (r & 7)) << 3)] = o;
    }
    __syncthreads();

    // qkv GEMM: wave w covers output cols [w*192, (w+1)*192); B-frags from L2
    {
        f32x4 qacc[12] = {};
        int n0w = w * 192;
        #pragma unroll
        for (int k0 = 0; k0 < 256; k0 += 32) {
            int r = lane & 15;
            int kk = k0 + (lane >> 4) * 8;
            int ck = kk >> 3;
            bf16x8 af = *(const bf16x8*)(const void*)&As[r * 256 + ((ck ^ (r & 7)) << 3)];
            #pragma unroll
            for (int fn = 0; fn < 12; fn++) {
                int nn2 = n0w + fn * 16 + (lane & 15);
                bf16x8 bv = *(const bf16x8*)(const void*)((const short*)wqkv16 + nn2 * 256 + kk);
                qacc[fn] = __builtin_amdgcn_mfma_f32_16x16x32_bf16(af, bv, qacc[fn], 0, 0, 0);
            }
        }
        __syncthreads();   // As fully consumed before ao_s (alias) is written later; qkvs writes begin
        #pragma unroll
        for (int fn = 0; fn < 12; fn++)
            #pragma unroll
            for (int r4 = 0; r4 < 4; r4++) {
                int row = (lane >> 4) * 4 + r4;
                if (row < 14) qkvs[row * 768 + n0w + fn * 16 + (lane & 15)] = qacc[fn][r4];
            }
    }
    __syncthreads();

    // attention scores (softmax over HEADS)
    for (int t = tid; t < 784; t += 256) {
        int bb = t / 392, r = t % 392, h = r / 49, ij = r % 49, i = ij / 7, j = ij % 7;
        const float* qp = qkvs + (bb * 7 + i) * 768 + h * 32;
        const float* kp = qkvs + (bb * 7 + j) * 768 + 256 + h * 32;
        float acc = 0.f;
        #pragma unroll
        for (int d = 0; d < 32; d++) acc += qp[d] * kp[d];
        as_[bb][h][ij] = acc * 0.17677669529663689f;
    }
    __syncthreads();
    if (tid < 98) {
        int bb = tid / 49, ij = tid % 49;
        float m = -INFINITY;
        #pragma unroll
        for (int h = 0; h < 8; h++) m = fmaxf(m, as_[bb][h][ij]);
        float e[8], sum = 0.f;
        #pragma unroll
        for (int h = 0; h < 8; h++) { e[h] = __expf(as_[bb][h][ij] - m); sum += e[h]; }
        float inv = 1.f / sum;
        #pragma unroll
        for (int h = 0; h < 8; h++) as_[bb][h][ij] = e[h] * inv;
    }
    __syncthreads();
    // ao rows (pads zero) -> registers first, then swizzled store into ao_s (aliases As, now dead)
    for (int t = tid; t < 16 * 256; t += 256) {
        int tl = t >> 8, col = t & 255;
        float acc = 0.f;
        if (tl < 14) {
            int bb = tl / 7, i = tl % 7, h = col >> 5;
            const float* ap = &as_[bb][h][i * 7];
            const float* vp = qkvs + (bb * 7) * 768 + 512 + col;
            #pragma unroll
            for (int j = 0; j < 7; j++) acc += ap[j] * vp[j * 768];
        }
        int c16 = col >> 3;
        union { __hip_bfloat16 h2; short s2; } u; u.h2 = __float2bfloat16(acc);
        ao_s[tl * 256 + ((c16 ^ (tl & 7)) << 3) + (col & 7)] = u.s2;
    }
    __syncthreads();
    // proj MFMA: wave w -> output cols n0 = w*64; B direct from L2 (wproj16 [N][K])
    f32x4 pacc[4] = {};
    int n0 = w * 64;
    #pragma unroll
    for (int k0 = 0; k0 < 256; k0 += 32) {
        int rowa = lane & 15;
        int kk = k0 + (lane >> 4) * 8;
        int c16a = kk >> 3;
        bf16x8 af = *(const bf16x8*)(const void*)&ao_s[rowa * 256 + ((c16a ^ (rowa & 7)) << 3)];
        #pragma unroll
        for (int fn = 0; fn < 4; fn++) {
            int n = n0 + fn * 16 + (lane & 15);
            bf16x8 bfv = *(const bf16x8*)(const void*)((const short*)wproj16 + n * 256 + kk);
            pacc[fn] = __builtin_amdgcn_mfma_f32_16x16x32_bf16(af, bfv, pacc[fn], 0, 0, 0);
        }
    }
    __syncthreads();   // qkvs (alias Ct) fully dead; ao_s reads done
    #pragma unroll
    for (int fn = 0; fn < 4; fn++)
        #pragma unroll
        for (int r4 = 0; r4 < 4; r4++) {
            int o = n0 + fn * 16 + (lane & 15);
            int t = (lane >> 4) * 4 + r4;
            Ct[o * 17 + t] = pacc[fn][r4];
        }
    __syncthreads();
    // residual(BN(xraw)) + transposed write: thread = output channel o
    int o = tid;
    int n = token0 / 210, rem0 = token0 % 210;   // 210 = 15*14: never straddles n
    float* op = outp + ((long long)(n * 256 + o)) * 210 + rem0;
    float sc = ssl[o], sh = ssl[256 + o];
    #pragma unroll
    for (int t2 = 0; t2 < 14; t2 += 2) {
        float2 v;
        v.x = Ct[o * 17 + t2]     + xraw[(long long)(token0 + t2) * 256 + o] * sc + sh;
        v.y = Ct[o * 17 + t2 + 1] + xraw[(long long)(token0 + t2 + 1) * 256 + o] * sc + sh;
        *(float2*)(op + t2) = v;
    }
}

extern "C" void kernel_launch(void* const* d_in, const int* in_sizes, int n_in,
                              void* d_out, int out_size, void* d_ws, size_t ws_size,
                              hipStream_t stream) {
    const float* sil   = (const float*)d_in[0];
    const float* pose  = (const float*)d_in[1];
    const float* fcbin = (const float*)d_in[2];
    const float* gamma = (const float*)d_in[3];
    const float* beta  = (const float*)d_in[4];
    const float* wqkv  = (const float*)d_in[5];
    const float* wproj = (const float*)d_in[6];
    const int*   minidx= (const int*)d_in[7];
    float* out = (float*)d_out;

    float* ws = (float*)d_ws;
    __hip_bfloat16* fuse16   = (__hip_bfloat16*)ws;             // 5,160,960 bf16
    float* xraw    = ws + 2580480;                              // 860,160 f32 (ldc=1792 view)
    float* partial = ws + 3440640;                              // 28,672
    __hip_bfloat16* wqkv16   = (__hip_bfloat16*)(ws + 3469312); // 196,608 bf16
    __hip_bfloat16* wproj16  = (__hip_bfloat16*)(ws + 3567616); // 65,536 bf16
    __hip_bfloat16* fcbinT16 = (__hip_bfloat16*)(ws + 3600384); // 2,752,512 bf16

    prep<<<7216, 256, 0, stream>>>(sil, minidx, wqkv, wproj, fcbin, pose,
                                   fuse16, wqkv16, wproj16, fcbinT16);
    gemm_fc<<<dim3(8, 4, 7), 512, 0, stream>>>(fuse16, fcbinT16, xraw, partial);
    qkvattn<<<240, 256, 0, stream>>>(xraw, wqkv16, wproj16, partial, gamma, beta, out);
}